// Round 10
// baseline (343.876 us; speedup 1.0000x reference)
//
#include <hip/hip_runtime.h>

// ---------------------------------------------------------------------------
// GCN 3-layer fused pipeline for MI355X.
//   Layer l: H = bf16mfma(A_bf16 @ Wl_bf16) -> hbuf (bf16)
//   agg[n]  = sum_{e in row(n)} w_e * H[src_e]   (self-loop is a regular edge)
//   y = BN/bias epilogue (folded scale/shift) -> bf16 (L1,L2) / f32 (L3)
// CSR built per call via deterministic binning (dst-bucket, LDS cursors).
// agg is COLUMN-SLICED: blockIdx&7 -> column group (16 cols = 32B of row);
// round-robin workgroup->XCD dispatch pins each group to one XCD, so the
// per-XCD hbuf footprint is N*64B = 3.2MB < 4MB L2 -> gathers become L2 hits.
// ---------------------------------------------------------------------------

#define NCHUNK 256   // edge chunks (pass A/C blocks)
#define BSHIFT 8     // dsts per bucket = 256
#define BWID 256
#define ECAP 8192    // LDS cw stage capacity per bucket (mean ~4340)

typedef __attribute__((ext_vector_type(8))) short bf16x8;
typedef __attribute__((ext_vector_type(4))) float f32x4;

__device__ __forceinline__ float blo(unsigned p) { return __uint_as_float(p << 16); }
__device__ __forceinline__ float bhi(unsigned p) { return __uint_as_float(p & 0xffff0000u); }
__device__ __forceinline__ unsigned short f2b(float f) {
  unsigned u = __float_as_uint(f);
  unsigned r = (u + 0x7fffu + ((u >> 16) & 1u)) >> 16;  // RTNE
  return (unsigned short)r;
}

// ---- weight prep + BN fold ------------------------------------------------
__global__ void wprep_kernel(const float* __restrict__ W1, const float* __restrict__ W2,
                             const float* __restrict__ W3,
                             const float* __restrict__ b1, const float* __restrict__ g1,
                             const float* __restrict__ be1, const float* __restrict__ m1,
                             const float* __restrict__ v1,
                             const float* __restrict__ b2, const float* __restrict__ g2,
                             const float* __restrict__ be2, const float* __restrict__ m2,
                             const float* __restrict__ v2,
                             unsigned short* __restrict__ Wt1,
                             unsigned short* __restrict__ Wt2,
                             unsigned short* __restrict__ Wt3,
                             float* __restrict__ sc1, float* __restrict__ sh1,
                             float* __restrict__ sc2, float* __restrict__ sh2) {
  int i = blockIdx.x * 256 + threadIdx.x;
  if (i < 16384) {
    int k = i >> 7, c = i & 127;
    Wt1[c * 128 + k] = f2b(W1[i]);
  } else if (i < 32768) {
    int j = i - 16384; int k = j >> 7, c = j & 127;
    Wt2[c * 128 + k] = f2b(W2[j]);
  } else if (i < 40960) {
    int j = i - 32768; int k = j >> 6, c = j & 63;
    Wt3[c * 128 + k] = f2b(W3[j]);
  } else if (i < 41088) {
    int c = i - 40960;
    float s = g1[c] * rsqrtf(v1[c] + 1e-5f);
    sc1[c] = s; sh1[c] = (b1[c] - m1[c]) * s + be1[c];
  } else if (i < 41216) {
    int c = i - 41088;
    float s = g2[c] * rsqrtf(v2[c] + 1e-5f);
    sc2[c] = s; sh2[c] = (b2[c] - m2[c]) * s + be2[c];
  }
}

// ---- pass A: per-chunk bucket histogram (self dtype-detect) ---------------
__global__ __launch_bounds__(256) void bin_hist_kernel(
    const int* __restrict__ ei32, const long long* __restrict__ ei64,
    int* __restrict__ counts, int E, int nbk) {
  __shared__ int hist[BWID];
  __shared__ int s_is32;
  int k = blockIdx.x, t = threadIdx.x;
  hist[t] = 0;
  if (t == 0) s_is32 = 0;
  int CH = (E + NCHUNK - 1) / NCHUNK;
  int e0 = k * CH, e1 = min(e0 + CH, E);
  __syncthreads();
  // int64 data: odd words are high halves == 0; int32: random node ids.
  if (t < 64 && e0 + t < E && ei32[2 * (e0 + t) + 1] != 0) atomicOr(&s_is32, 1);
  __syncthreads();
  int is32 = s_is32;
  for (int e = e0 + t; e < e1; e += 256) {
    int d = is32 ? ei32[E + e] : (int)ei64[E + e];
    atomicAdd(&hist[d >> BSHIFT], 1);
  }
  __syncthreads();
  if (t < nbk) counts[t * NCHUNK + k] = hist[t];
}

// ---- scan over counts (2 kernels, CHUNK=8192 so nb<=64) -------------------
template <int CHUNK>
__global__ __launch_bounds__(256) void scan_partial_kernel(
    const int* __restrict__ src, int* __restrict__ bsum, int n) {
  __shared__ int wsum[4];
  constexpr int EL = CHUNK / 256;
  int b = blockIdx.x, t = threadIdx.x;
  int lane = t & 63, wv = t >> 6;
  int s = 0;
  int i0 = b * CHUNK + t * EL;
#pragma unroll
  for (int q = 0; q < EL / 4; ++q) {
    int i = i0 + q * 4;
    if (i + 3 < n) {
      int4 d4 = *(const int4*)&src[i];
      s += d4.x + d4.y + d4.z + d4.w;
    } else {
      for (int r = 0; r < 4; ++r) if (i + r < n) s += src[i + r];
    }
  }
#pragma unroll
  for (int off = 32; off; off >>= 1) s += __shfl_xor(s, off);
  if (lane == 0) wsum[wv] = s;
  __syncthreads();
  if (t == 0) bsum[b] = wsum[0] + wsum[1] + wsum[2] + wsum[3];
}

template <int CHUNK>
__global__ __launch_bounds__(256) void scan_write_kernel(
    const int* __restrict__ src, const int* __restrict__ bsum,
    int* __restrict__ outp, int n, int nb) {
  constexpr int EL = CHUNK / 256;
  __shared__ int woff[4];
  __shared__ int s_boff;
  int b = blockIdx.x, t = threadIdx.x;
  int lane = t & 63, wv = t >> 6;
  if (t < 64) {
    int v = (t < nb) ? bsum[t] : 0;
    int ic = v;
#pragma unroll
    for (int off = 1; off < 64; off <<= 1) {
      int u = __shfl_up(ic, off);
      if (t >= off) ic += u;
    }
    if (t == b) s_boff = ic - v;
    if (b == nb - 1 && t == 63) outp[n] = ic;  // total
  }
  int vals[EL];
  int i0 = b * CHUNK + t * EL;
#pragma unroll
  for (int q = 0; q < EL / 4; ++q) {
    int i = i0 + q * 4;
    int4 d4 = make_int4(0, 0, 0, 0);
    if (i + 3 < n) d4 = *(const int4*)&src[i];
    else {
      if (i < n) d4.x = src[i];
      if (i + 1 < n) d4.y = src[i + 1];
      if (i + 2 < n) d4.z = src[i + 2];
    }
    vals[q * 4] = d4.x; vals[q * 4 + 1] = d4.y;
    vals[q * 4 + 2] = d4.z; vals[q * 4 + 3] = d4.w;
  }
  int tsum = 0;
#pragma unroll
  for (int q = 0; q < EL; ++q) tsum += vals[q];
  int inc = tsum;
#pragma unroll
  for (int off = 1; off < 64; off <<= 1) {
    int u = __shfl_up(inc, off);
    if (lane >= off) inc += u;
  }
  if (lane == 63) woff[wv] = inc;
  __syncthreads();
  if (t == 0) {
    int r = 0;
#pragma unroll
    for (int w = 0; w < 4; ++w) { int sw = woff[w]; woff[w] = r; r += sw; }
  }
  __syncthreads();
  int p = inc - tsum + woff[wv] + s_boff;
#pragma unroll
  for (int q = 0; q < EL; ++q) {
    int i = i0 + q;
    if (i < n) outp[i] = p;
    p += vals[q];
  }
}

// ---- pass C: scatter packed (src | dst_low<<20) into bucket runs ----------
__global__ __launch_bounds__(256) void bin_scatter_kernel(
    const int* __restrict__ ei32, const long long* __restrict__ ei64,
    const int* __restrict__ offs, unsigned* __restrict__ pairs, int E, int nbk) {
  __shared__ int cur[BWID];
  __shared__ int s_is32;
  int k = blockIdx.x, t = threadIdx.x;
  if (t < nbk) cur[t] = offs[t * NCHUNK + k];
  if (t == 0) s_is32 = 0;
  int CH = (E + NCHUNK - 1) / NCHUNK;
  int e0 = k * CH, e1 = min(e0 + CH, E);
  __syncthreads();
  if (t < 64 && e0 + t < E && ei32[2 * (e0 + t) + 1] != 0) atomicOr(&s_is32, 1);
  __syncthreads();
  int is32 = s_is32;
  for (int e = e0 + t; e < e1; e += 256) {
    int s, d;
    if (is32) { s = ei32[e]; d = ei32[E + e]; }
    else      { s = (int)ei64[e]; d = (int)ei64[E + e]; }
    int pos = atomicAdd(&cur[d >> BSHIFT], 1);
    pairs[pos] = (unsigned)s | ((unsigned)(d & (BWID - 1)) << 20);
  }
}

// ---- p1: per-bucket degree -> rowptr (incl self), dinv --------------------
__global__ __launch_bounds__(256) void bucket_p1_kernel(
    const unsigned* __restrict__ pairs, const int* __restrict__ offs,
    int* __restrict__ rowptr, float* __restrict__ dinv, int E, int n) {
  __shared__ int deg[BWID];
  __shared__ int woff[4];
  int b = blockIdx.x, t = threadIdx.x;
  int lane = t & 63, wv = t >> 6;
  deg[t] = 0;
  __syncthreads();
  int basep = offs[b * NCHUNK];
  int endp = offs[(b + 1) * NCHUNK];
  for (int i = basep + t; i < endp; i += 256)
    atomicAdd(&deg[pairs[i] >> 20], 1);
  __syncthreads();
  int dg = deg[t];
  int inc = dg + 1;  // +1 self edge
#pragma unroll
  for (int off = 1; off < 64; off <<= 1) {
    int u = __shfl_up(inc, off);
    if (lane >= off) inc += u;
  }
  if (lane == 63) woff[wv] = inc;
  __syncthreads();
  if (t == 0) {
    int r = 0;
#pragma unroll
    for (int w = 0; w < 4; ++w) { int sw = woff[w]; woff[w] = r; r += sw; }
  }
  __syncthreads();
  int exc = inc - (dg + 1) + woff[wv];
  int cwbase = basep + b * BWID;  // preceding buckets contributed 256 selfs each
  int idx = b * BWID + t;
  if (idx < n) {
    rowptr[idx] = cwbase + exc;
    dinv[idx] = rsqrtf((float)(dg + 1));
  }
  if (b == 0 && t == 0) rowptr[n] = E + n;
}

// ---- p2: assemble (src, w) per bucket in LDS (self first), coalesced out --
__global__ __launch_bounds__(256) void bucket_p2_kernel(
    const unsigned* __restrict__ pairs, const int* __restrict__ offs,
    const int* __restrict__ rowptr, const float* __restrict__ dinv,
    uint2* __restrict__ cw, int E, int n) {
  __shared__ int cur[BWID];
  __shared__ float dsl[BWID];
  __shared__ int stage_s[ECAP];
  __shared__ float stage_w[ECAP];
  int b = blockIdx.x, t = threadIdx.x;
  int basep = offs[b * NCHUNK];
  int endp = offs[(b + 1) * NCHUNK];
  int cwbase = basep + b * BWID;
  int idx = b * BWID + t;
  int nreal = min(n - b * BWID, BWID);
  float dv = (t < nreal) ? dinv[idx] : 0.f;
  dsl[t] = dv;
  cur[t] = (t < nreal) ? rowptr[idx] - cwbase : 0;
  __syncthreads();
  if (t < nreal) {  // self edge first in each row
    int pos = atomicAdd(&cur[t], 1);
    if (pos < ECAP) { stage_s[pos] = idx; stage_w[pos] = dv * dv; }
    else cw[cwbase + pos] = make_uint2((unsigned)idx, __float_as_uint(dv * dv));
  }
  __syncthreads();
  for (int i = basep + t; i < endp; i += 256) {
    unsigned p = pairs[i];
    int s = (int)(p & 0xFFFFFu);
    int dl = (int)(p >> 20);
    int pos = atomicAdd(&cur[dl], 1);
    float w = dinv[s] * dsl[dl];
    if (pos < ECAP) { stage_s[pos] = s; stage_w[pos] = w; }
    else cw[cwbase + pos] = make_uint2((unsigned)s, __float_as_uint(w));
  }
  __syncthreads();
  int nE = (endp - basep) + nreal;
  int lim = min(nE, ECAP);
  for (int i = t; i < lim; i += 256)
    cw[cwbase + i] = make_uint2((unsigned)stage_s[i], __float_as_uint(stage_w[i]));
}

// ---- MFMA bf16 GEMM: Y[n x HOUT](bf16) = A[n x 128] * Wt^T ----------------
template <int HOUT, int ABF16>
__global__ __launch_bounds__(256) void mgemm_kernel(
    const void* __restrict__ Ain, const unsigned short* __restrict__ Wt,
    unsigned short* __restrict__ Y, int n) {
  constexpr int NT = HOUT;
  __shared__ unsigned char AsB[64 * 256];
  __shared__ unsigned char BsB[NT * 256];
  int t = threadIdx.x;
  int row0 = blockIdx.x * 64;

  if constexpr (ABF16) {
    const unsigned short* A = (const unsigned short*)Ain;
#pragma unroll
    for (int jj = 0; jj < 4; ++jj) {
      int f = t + 256 * jj; int r = f >> 4, kq = f & 15;
      uint4 v = make_uint4(0, 0, 0, 0);
      if (row0 + r < n) v = *(const uint4*)&A[(size_t)(row0 + r) * 128 + kq * 8];
      *(uint4*)&AsB[r * 256 + ((kq * 16) ^ ((r & 15) << 4))] = v;
    }
  } else {
    const float* A = (const float*)Ain;
#pragma unroll
    for (int jj = 0; jj < 8; ++jj) {
      int f = t + 256 * jj; int r = f >> 5, kq = f & 31;
      float4 v = make_float4(0.f, 0.f, 0.f, 0.f);
      if (row0 + r < n) v = *(const float4*)&A[(size_t)(row0 + r) * 128 + kq * 4];
      unsigned two0 = (unsigned)f2b(v.x) | ((unsigned)f2b(v.y) << 16);
      unsigned two1 = (unsigned)f2b(v.z) | ((unsigned)f2b(v.w) << 16);
      uint2 o = make_uint2(two0, two1);
      *(uint2*)&AsB[r * 256 + ((kq * 8) ^ ((r & 15) << 4))] = o;
    }
  }
#pragma unroll
  for (int jj = 0; jj < NT / 16; ++jj) {
    int f = t + 256 * jj; int c = f >> 4, kq = f & 15;
    uint4 v = *(const uint4*)&Wt[(size_t)c * 128 + kq * 8];
    *(uint4*)&BsB[c * 256 + ((kq * 16) ^ ((c & 15) << 4))] = v;
  }
  __syncthreads();

  int l = t & 63, wid = t >> 6;
  constexpr int WC = NT / 2;
  constexpr int NI = WC / 16;
  int wr = (wid >> 1) * 32, wc = (wid & 1) * WC;
  int lr = l & 15, lk = (l >> 4) * 16;

  f32x4 acc[2][NI] = {};
#pragma unroll
  for (int ks = 0; ks < 4; ++ks) {
    bf16x8 a[2], b[NI];
#pragma unroll
    for (int mi = 0; mi < 2; ++mi) {
      int r = wr + mi * 16 + lr;
      a[mi] = *(const bf16x8*)&AsB[r * 256 + ((ks * 64 + lk) ^ ((r & 15) << 4))];
    }
#pragma unroll
    for (int ni = 0; ni < NI; ++ni) {
      int c = wc + ni * 16 + lr;
      b[ni] = *(const bf16x8*)&BsB[c * 256 + ((ks * 64 + lk) ^ ((c & 15) << 4))];
    }
#pragma unroll
    for (int mi = 0; mi < 2; ++mi)
#pragma unroll
      for (int ni = 0; ni < NI; ++ni)
        acc[mi][ni] = __builtin_amdgcn_mfma_f32_16x16x32_bf16(a[mi], b[ni],
                                                              acc[mi][ni], 0, 0, 0);
  }

#pragma unroll
  for (int mi = 0; mi < 2; ++mi) {
#pragma unroll
    for (int reg = 0; reg < 4; ++reg) {
      int gr = row0 + wr + mi * 16 + (l >> 4) * 4 + reg;
      if (gr < n) {
#pragma unroll
        for (int ni = 0; ni < NI; ++ni) {
          int gc = wc + ni * 16 + lr;
          Y[(size_t)gr * HOUT + gc] = f2b(acc[mi][ni][reg]);
        }
      }
    }
  }
}

// ---- column-sliced aggregation -------------------------------------------
// blockIdx&7 = XCD slot. HOUT=128: colgroup = slot (8 groups x 16 cols).
// HOUT=64: colgroup = slot>>1 (4 groups x 16 cols), slot&1 = node parity.
// Wave = 64 lanes = 8 edge-phases x 8 col-sublanes (uint = 2 cols each).
// Each wave does 2 nodes; 4 waves/block -> 8 nodes per block.
template <int HOUT, bool BN, bool OUTBF>
__global__ __launch_bounds__(256) void agg_kernel(
    const unsigned short* __restrict__ h, const int* __restrict__ rowptr,
    const uint2* __restrict__ cw,
    const float* __restrict__ sc, const float* __restrict__ sh,
    void* __restrict__ out, int n_nodes) {
  constexpr int RWU = HOUT / 2;  // uints per row (64 or 32)
  int grp = blockIdx.x & 7;
  int blk = blockIdx.x >> 3;
  int wv = threadIdx.x >> 6;
  int lane = threadIdx.x & 63;
  int phase = lane >> 3;   // 0..7: edge slot
  int sub = lane & 7;      // col pair within 16-col group
  int cg, n0;
  if constexpr (HOUT == 128) {
    cg = grp;
    n0 = blk * 8 + wv * 2;
  } else {
    cg = grp >> 1;
    n0 = (blk * 2 + (grp & 1)) * 8 + wv * 2;
  }
  const unsigned* hu = (const unsigned*)h;
  int cbase = cg * 8;

#pragma unroll
  for (int ni = 0; ni < 2; ++ni) {
    int n = n0 + ni;
    if (n >= n_nodes) continue;  // wave-uniform
    int beg = rowptr[n], end = rowptr[n + 1];
    float a0 = 0.f, a1 = 0.f;
    for (int j = beg; j < end; j += 32) {
      int j0 = j + phase, j1 = j0 + 8, j2 = j0 + 16, j3 = j0 + 24;
      uint2 e0 = cw[j0 < end ? j0 : end - 1];
      uint2 e1 = cw[j1 < end ? j1 : end - 1];
      uint2 e2 = cw[j2 < end ? j2 : end - 1];
      uint2 e3 = cw[j3 < end ? j3 : end - 1];
      unsigned v0 = hu[(size_t)e0.x * RWU + cbase + sub];
      unsigned v1 = hu[(size_t)e1.x * RWU + cbase + sub];
      unsigned v2 = hu[(size_t)e2.x * RWU + cbase + sub];
      unsigned v3 = hu[(size_t)e3.x * RWU + cbase + sub];
      float w0 = (j0 < end) ? __uint_as_float(e0.y) : 0.f;
      float w1 = (j1 < end) ? __uint_as_float(e1.y) : 0.f;
      float w2 = (j2 < end) ? __uint_as_float(e2.y) : 0.f;
      float w3 = (j3 < end) ? __uint_as_float(e3.y) : 0.f;
      a0 = fmaf(w0, blo(v0), a0); a1 = fmaf(w0, bhi(v0), a1);
      a0 = fmaf(w1, blo(v1), a0); a1 = fmaf(w1, bhi(v1), a1);
      a0 = fmaf(w2, blo(v2), a0); a1 = fmaf(w2, bhi(v2), a1);
      a0 = fmaf(w3, blo(v3), a0); a1 = fmaf(w3, bhi(v3), a1);
    }
    // reduce over 8 phases (stride-8 lane groups)
    a0 += __shfl_xor(a0, 32); a1 += __shfl_xor(a1, 32);
    a0 += __shfl_xor(a0, 16); a1 += __shfl_xor(a1, 16);
    a0 += __shfl_xor(a0, 8);  a1 += __shfl_xor(a1, 8);
    if (phase == 0) {
      int c0 = (cbase + sub) * 2;
      float y0, y1;
      if constexpr (BN) {
        y0 = fmaxf(fmaf(a0, sc[c0], sh[c0]), 0.f);
        y1 = fmaxf(fmaf(a1, sc[c0 + 1], sh[c0 + 1]), 0.f);
      } else {
        y0 = a0 + sh[c0];
        y1 = a1 + sh[c0 + 1];
      }
      if constexpr (OUTBF) {
        unsigned pk = (unsigned)f2b(y0) | ((unsigned)f2b(y1) << 16);
        ((unsigned*)out)[(size_t)n * RWU + cbase + sub] = pk;
      } else {
        float2 o; o.x = y0; o.y = y1;
        *(float2*)&((float*)out)[(size_t)n * HOUT + c0] = o;
      }
    }
  }
}

extern "C" void kernel_launch(void* const* d_in, const int* in_sizes, int n_in,
                              void* d_out, int out_size, void* d_ws, size_t ws_size,
                              hipStream_t stream) {
  const float* x = (const float*)d_in[0];
  const int* ei32 = (const int*)d_in[1];
  const long long* ei64 = (const long long*)d_in[1];
  const float* W1 = (const float*)d_in[2];
  const float* b1 = (const float*)d_in[3];
  const float* g1 = (const float*)d_in[4];
  const float* be1 = (const float*)d_in[5];
  const float* m1 = (const float*)d_in[6];
  const float* v1 = (const float*)d_in[7];
  const float* W2 = (const float*)d_in[8];
  const float* b2 = (const float*)d_in[9];
  const float* g2 = (const float*)d_in[10];
  const float* be2 = (const float*)d_in[11];
  const float* m2 = (const float*)d_in[12];
  const float* v2 = (const float*)d_in[13];
  const float* W3 = (const float*)d_in[14];
  const float* b3 = (const float*)d_in[15];

  const int N = in_sizes[0] / 128;        // 50000
  const int E = in_sizes[1] / 2;          // 800000
  const int NBK = (N + BWID - 1) / BWID;  // 196 (<= 256)
  const int NC = NBK * NCHUNK;            // 50176

  char* ws = (char*)d_ws;
  size_t off = 0;
  auto alloc = [&](size_t bytes) -> void* {
    void* p = ws + off;
    off = (off + bytes + 255) & ~(size_t)255;
    return p;
  };
  float* dinv = (float*)alloc((size_t)N * 4);
  int* rowptr = (int*)alloc((size_t)(N + 1) * 4);
  int* counts = (int*)alloc((size_t)NC * 4);
  int* offs = (int*)alloc((size_t)(NC + 1) * 4);
  unsigned* pairs = (unsigned*)alloc((size_t)E * 4);
  uint2* cw = (uint2*)alloc((size_t)(E + N) * 8);
  int* bsum = (int*)alloc(64 * 4);
  unsigned short* wt1 = (unsigned short*)alloc(128 * 128 * 2);
  unsigned short* wt2 = (unsigned short*)alloc(128 * 128 * 2);
  unsigned short* wt3 = (unsigned short*)alloc(128 * 64 * 2);
  float* sc1 = (float*)alloc(128 * 4);
  float* sh1 = (float*)alloc(128 * 4);
  float* sc2 = (float*)alloc(128 * 4);
  float* sh2 = (float*)alloc(128 * 4);
  unsigned short* hbuf = (unsigned short*)alloc((size_t)N * 128 * 2);  // bf16
  unsigned short* ybuf = (unsigned short*)alloc((size_t)N * 128 * 2);  // bf16
  (void)ws_size;

  wprep_kernel<<<161, 256, 0, stream>>>(W1, W2, W3, b1, g1, be1, m1, v1,
                                        b2, g2, be2, m2, v2,
                                        wt1, wt2, wt3, sc1, sh1, sc2, sh2);

  // CSR build
  bin_hist_kernel<<<NCHUNK, 256, 0, stream>>>(ei32, ei64, counts, E, NBK);
  int nbC = (NC + 8191) / 8192;  // 7
  scan_partial_kernel<8192><<<nbC, 256, 0, stream>>>(counts, bsum, NC);
  scan_write_kernel<8192><<<nbC, 256, 0, stream>>>(counts, bsum, offs, NC, nbC);
  bin_scatter_kernel<<<NCHUNK, 256, 0, stream>>>(ei32, ei64, offs, pairs, E, NBK);
  bucket_p1_kernel<<<NBK, 256, 0, stream>>>(pairs, offs, rowptr, dinv, E, N);
  bucket_p2_kernel<<<NBK, 256, 0, stream>>>(pairs, offs, rowptr, dinv, cw, E, N);

  int gb = (N + 63) / 64;
  int chunks = (N + 7) / 8;                 // 8 nodes per block
  int ag128 = chunks * 8;                   // x8 col groups
  int ag64 = ((chunks + 1) / 2) * 8;        // 4 groups x parity split

  // layer 1
  mgemm_kernel<128, 0><<<gb, 256, 0, stream>>>(x, wt1, hbuf, N);
  agg_kernel<128, true, true><<<ag128, 256, 0, stream>>>(hbuf, rowptr, cw,
                                                         sc1, sh1, ybuf, N);
  // layer 2
  mgemm_kernel<128, 1><<<gb, 256, 0, stream>>>(ybuf, wt2, hbuf, N);
  agg_kernel<128, true, true><<<ag128, 256, 0, stream>>>(hbuf, rowptr, cw,
                                                         sc2, sh2, ybuf, N);
  // layer 3
  mgemm_kernel<64, 1><<<gb, 256, 0, stream>>>(ybuf, wt3, hbuf, N);
  agg_kernel<64, false, false><<<ag64, 256, 0, stream>>>(hbuf, rowptr, cw,
                                                         nullptr, b3, d_out, N);
}

// Round 11
// 190.119 us; speedup vs baseline: 1.8087x; 1.8087x over previous
//
#include <hip/hip_runtime.h>

// ---------------------------------------------------------------------------
// GCN 3-layer fused pipeline for MI355X.  (Round-5 structure restored.)
//   Layer l: H = bf16mfma(A_bf16 @ Wl_bf16) -> hbuf (bf16)
//   agg[n]  = dinv[n]^2*H[n] + sum_{e:dst=n} w_e*H[src_e]  (f32 acc)
//   y = BN/bias epilogue (folded scale/shift) -> bf16 (L1,L2) / f32 (L3)
// CSR built per call via deterministic binning. Edge array cw[e]=(src,w).
// agg: phased lanes (NPH edge phases x GL col-lanes), uint2 (4 bf16)/lane,
// 8 gathers in flight per phase group (latency-bound loop).
// ---------------------------------------------------------------------------

#define SCAN_CHUNK 1024
#define NCHUNK 256   // edge chunks (pass A/C blocks)
#define BSHIFT 8     // dsts per bucket = 256
#define BWID 256
#define ECAP 8192    // LDS cw stage capacity per bucket (mean ~4350)

typedef __attribute__((ext_vector_type(8))) short bf16x8;
typedef __attribute__((ext_vector_type(4))) float f32x4;

__device__ __forceinline__ float blo(unsigned p) { return __uint_as_float(p << 16); }
__device__ __forceinline__ float bhi(unsigned p) { return __uint_as_float(p & 0xffff0000u); }
__device__ __forceinline__ unsigned short f2b(float f) {
  unsigned u = __float_as_uint(f);
  unsigned r = (u + 0x7fffu + ((u >> 16) & 1u)) >> 16;  // RTNE
  return (unsigned short)r;
}

// ---- weight prep + BN fold ------------------------------------------------
__global__ void wprep_kernel(const float* __restrict__ W1, const float* __restrict__ W2,
                             const float* __restrict__ W3,
                             const float* __restrict__ b1, const float* __restrict__ g1,
                             const float* __restrict__ be1, const float* __restrict__ m1,
                             const float* __restrict__ v1,
                             const float* __restrict__ b2, const float* __restrict__ g2,
                             const float* __restrict__ be2, const float* __restrict__ m2,
                             const float* __restrict__ v2,
                             unsigned short* __restrict__ Wt1,
                             unsigned short* __restrict__ Wt2,
                             unsigned short* __restrict__ Wt3,
                             float* __restrict__ sc1, float* __restrict__ sh1,
                             float* __restrict__ sc2, float* __restrict__ sh2) {
  int i = blockIdx.x * 256 + threadIdx.x;
  if (i < 16384) {
    int k = i >> 7, c = i & 127;
    Wt1[c * 128 + k] = f2b(W1[i]);
  } else if (i < 32768) {
    int j = i - 16384; int k = j >> 7, c = j & 127;
    Wt2[c * 128 + k] = f2b(W2[j]);
  } else if (i < 40960) {
    int j = i - 32768; int k = j >> 6, c = j & 63;
    Wt3[c * 128 + k] = f2b(W3[j]);
  } else if (i < 41088) {
    int c = i - 40960;
    float s = g1[c] * rsqrtf(v1[c] + 1e-5f);
    sc1[c] = s; sh1[c] = (b1[c] - m1[c]) * s + be1[c];
  } else if (i < 41216) {
    int c = i - 41088;
    float s = g2[c] * rsqrtf(v2[c] + 1e-5f);
    sc2[c] = s; sh2[c] = (b2[c] - m2[c]) * s + be2[c];
  }
}

// ---- pass A: per-chunk bucket histogram (self dtype-detect) ---------------
__global__ __launch_bounds__(256) void bin_hist_kernel(
    const int* __restrict__ ei32, const long long* __restrict__ ei64,
    int* __restrict__ counts, int E, int nbk) {
  __shared__ int hist[BWID];
  __shared__ int s_is32;
  int k = blockIdx.x, t = threadIdx.x;
  hist[t] = 0;
  if (t == 0) s_is32 = 0;
  int CH = (E + NCHUNK - 1) / NCHUNK;
  int e0 = k * CH, e1 = min(e0 + CH, E);
  __syncthreads();
  // int64 data: odd words are high halves == 0; int32: random node ids.
  if (t < 64 && e0 + t < E && ei32[2 * (e0 + t) + 1] != 0) atomicOr(&s_is32, 1);
  __syncthreads();
  int is32 = s_is32;
  for (int e = e0 + t; e < e1; e += 256) {
    int d = is32 ? ei32[E + e] : (int)ei64[E + e];
    atomicAdd(&hist[d >> BSHIFT], 1);
  }
  __syncthreads();
  if (t < nbk) counts[t * NCHUNK + k] = hist[t];
}

// ---- scan: partial sums ----------------------------------------------------
__global__ __launch_bounds__(256) void scan_partial_kernel(
    const int* __restrict__ src, int* __restrict__ bsum, int n) {
  __shared__ int wsum[4];
  int b = blockIdx.x, t = threadIdx.x;
  int lane = t & 63, wv = t >> 6;
  int i0 = b * SCAN_CHUNK + t * 4;
  int4 d4 = make_int4(0, 0, 0, 0);
  if (i0 + 3 < n) d4 = *(const int4*)&src[i0];
  else {
    if (i0 < n) d4.x = src[i0];
    if (i0 + 1 < n) d4.y = src[i0 + 1];
    if (i0 + 2 < n) d4.z = src[i0 + 2];
  }
  int s = d4.x + d4.y + d4.z + d4.w;
#pragma unroll
  for (int off = 32; off; off >>= 1) s += __shfl_xor(s, off);
  if (lane == 0) wsum[wv] = s;
  __syncthreads();
  if (t == 0) bsum[b] = wsum[0] + wsum[1] + wsum[2] + wsum[3];
}

// ---- scan: write (inline bsum scan; wave 0 redundantly scans <=64 sums) ---
template <bool DEG>
__global__ __launch_bounds__(256) void scan_write_kernel(
    const int* __restrict__ src, const int* __restrict__ bsum,
    int* __restrict__ outp, float* __restrict__ dinv, int n, int nb) {
  __shared__ int woff[4];
  __shared__ int s_boff;
  int b = blockIdx.x, t = threadIdx.x;
  int lane = t & 63, wv = t >> 6;
  if (t < 64) {
    int v = (t < nb) ? bsum[t] : 0;
    int ic = v;
#pragma unroll
    for (int off = 1; off < 64; off <<= 1) {
      int u = __shfl_up(ic, off);
      if (t >= off) ic += u;
    }
    if (t == b) s_boff = ic - v;
    if (b == nb - 1 && t == 63) outp[n] = ic;  // total
  }
  int i0 = b * SCAN_CHUNK + t * 4;
  int4 d4 = make_int4(0, 0, 0, 0);
  if (i0 + 3 < n) d4 = *(const int4*)&src[i0];
  else {
    if (i0 < n) d4.x = src[i0];
    if (i0 + 1 < n) d4.y = src[i0 + 1];
    if (i0 + 2 < n) d4.z = src[i0 + 2];
  }
  int tsum = d4.x + d4.y + d4.z + d4.w;
  int inc = tsum;
#pragma unroll
  for (int off = 1; off < 64; off <<= 1) {
    int u = __shfl_up(inc, off);
    if (lane >= off) inc += u;
  }
  if (lane == 63) woff[wv] = inc;
  __syncthreads();
  if (t == 0) {
    int r = 0;
#pragma unroll
    for (int w = 0; w < 4; ++w) { int sw = woff[w]; woff[w] = r; r += sw; }
  }
  __syncthreads();
  int p = inc - tsum + woff[wv] + s_boff;
  int dg[4] = {d4.x, d4.y, d4.z, d4.w};
#pragma unroll
  for (int j = 0; j < 4; ++j) {
    int i = i0 + j;
    if (i < n) {
      outp[i] = p;
      if constexpr (DEG) dinv[i] = rsqrtf((float)(dg[j] + 1));  // +1 self loop
      p += dg[j];
    }
  }
}

// ---- pass C: scatter packed (src | dst_low<<20) into bucketed runs --------
__global__ __launch_bounds__(256) void bin_scatter_kernel(
    const int* __restrict__ ei32, const long long* __restrict__ ei64,
    const int* __restrict__ offs, unsigned* __restrict__ pairs, int E, int nbk) {
  __shared__ int cur[BWID];
  __shared__ int s_is32;
  int k = blockIdx.x, t = threadIdx.x;
  if (t < nbk) cur[t] = offs[t * NCHUNK + k];
  if (t == 0) s_is32 = 0;
  int CH = (E + NCHUNK - 1) / NCHUNK;
  int e0 = k * CH, e1 = min(e0 + CH, E);
  __syncthreads();
  if (t < 64 && e0 + t < E && ei32[2 * (e0 + t) + 1] != 0) atomicOr(&s_is32, 1);
  __syncthreads();
  int is32 = s_is32;
  for (int e = e0 + t; e < e1; e += 256) {
    int s, d;
    if (is32) { s = ei32[e]; d = ei32[E + e]; }
    else      { s = (int)ei64[e]; d = (int)ei64[E + e]; }
    int pos = atomicAdd(&cur[d >> BSHIFT], 1);
    pairs[pos] = (unsigned)s | ((unsigned)(d & (BWID - 1)) << 20);
  }
}

// ---- pass D: per-bucket degree histogram ----------------------------------
__global__ __launch_bounds__(256) void bucket_deg_kernel(
    const unsigned* __restrict__ pairs, const int* __restrict__ offs,
    int* __restrict__ degi, int E, int n, int nbk) {
  __shared__ int deg[BWID];
  int b = blockIdx.x, t = threadIdx.x;
  deg[t] = 0;
  __syncthreads();
  int base = offs[b * NCHUNK];
  int end = (b + 1 < nbk) ? offs[(b + 1) * NCHUNK] : E;
  for (int i = base + t; i < end; i += 256) {
    atomicAdd(&deg[pairs[i] >> 20], 1);
  }
  __syncthreads();
  int idx = b * BWID + t;
  if (idx < n) degi[idx] = deg[t];
}

// ---- pass E: assemble (src, w) per bucket in LDS, write coalesced ---------
__global__ __launch_bounds__(256) void bucket_col_kernel(
    const unsigned* __restrict__ pairs, const int* __restrict__ offs,
    const int* __restrict__ rowptr, const float* __restrict__ dinv,
    uint2* __restrict__ cw, int E, int n, int nbk) {
  __shared__ int cur[BWID];
  __shared__ float dsl[BWID];
  __shared__ int stage_s[ECAP];
  __shared__ float stage_w[ECAP];
  int b = blockIdx.x, t = threadIdx.x;
  int rowbase = rowptr[b * BWID];
  int idx = b * BWID + t;
  cur[t] = ((idx < n) ? rowptr[idx] : rowptr[n]) - rowbase;
  dsl[t] = (idx < n) ? dinv[idx] : 0.f;
  __syncthreads();
  int base = offs[b * NCHUNK];
  int end = (b + 1 < nbk) ? offs[(b + 1) * NCHUNK] : E;
  for (int i = base + t; i < end; i += 256) {
    unsigned p = pairs[i];
    int s = (int)(p & 0xFFFFFu);
    int dl = (int)(p >> 20);
    int pos = atomicAdd(&cur[dl], 1);
    if (pos < ECAP) { stage_s[pos] = s; stage_w[pos] = dinv[s] * dsl[dl]; }
  }
  __syncthreads();
  int hi = b * BWID + BWID;
  int nE = ((hi < n) ? rowptr[hi] : rowptr[n]) - rowbase;
  for (int i = t; i < nE; i += 256)
    cw[rowbase + i] = make_uint2((unsigned)stage_s[i], __float_as_uint(stage_w[i]));
}

// ---- MFMA bf16 GEMM: Y[n x HOUT](bf16) = A[n x 128] * Wt^T ----------------
template <int HOUT, int ABF16>
__global__ __launch_bounds__(256) void mgemm_kernel(
    const void* __restrict__ Ain, const unsigned short* __restrict__ Wt,
    unsigned short* __restrict__ Y, int n) {
  constexpr int NT = HOUT;
  __shared__ unsigned char AsB[64 * 256];
  __shared__ unsigned char BsB[NT * 256];
  int t = threadIdx.x;
  int row0 = blockIdx.x * 64;

  if constexpr (ABF16) {
    const unsigned short* A = (const unsigned short*)Ain;
#pragma unroll
    for (int jj = 0; jj < 4; ++jj) {
      int f = t + 256 * jj; int r = f >> 4, kq = f & 15;
      uint4 v = make_uint4(0, 0, 0, 0);
      if (row0 + r < n) v = *(const uint4*)&A[(size_t)(row0 + r) * 128 + kq * 8];
      *(uint4*)&AsB[r * 256 + ((kq * 16) ^ ((r & 15) << 4))] = v;
    }
  } else {
    const float* A = (const float*)Ain;
#pragma unroll
    for (int jj = 0; jj < 8; ++jj) {
      int f = t + 256 * jj; int r = f >> 5, kq = f & 31;
      float4 v = make_float4(0.f, 0.f, 0.f, 0.f);
      if (row0 + r < n) v = *(const float4*)&A[(size_t)(row0 + r) * 128 + kq * 4];
      unsigned two0 = (unsigned)f2b(v.x) | ((unsigned)f2b(v.y) << 16);
      unsigned two1 = (unsigned)f2b(v.z) | ((unsigned)f2b(v.w) << 16);
      uint2 o = make_uint2(two0, two1);
      *(uint2*)&AsB[r * 256 + ((kq * 8) ^ ((r & 15) << 4))] = o;
    }
  }
#pragma unroll
  for (int jj = 0; jj < NT / 16; ++jj) {
    int f = t + 256 * jj; int c = f >> 4, kq = f & 15;
    uint4 v = *(const uint4*)&Wt[(size_t)c * 128 + kq * 8];
    *(uint4*)&BsB[c * 256 + ((kq * 16) ^ ((c & 15) << 4))] = v;
  }
  __syncthreads();

  int l = t & 63, wid = t >> 6;
  constexpr int WC = NT / 2;
  constexpr int NI = WC / 16;
  int wr = (wid >> 1) * 32, wc = (wid & 1) * WC;
  int lr = l & 15, lk = (l >> 4) * 16;

  f32x4 acc[2][NI] = {};
#pragma unroll
  for (int ks = 0; ks < 4; ++ks) {
    bf16x8 a[2], b[NI];
#pragma unroll
    for (int mi = 0; mi < 2; ++mi) {
      int r = wr + mi * 16 + lr;
      a[mi] = *(const bf16x8*)&AsB[r * 256 + ((ks * 64 + lk) ^ ((r & 15) << 4))];
    }
#pragma unroll
    for (int ni = 0; ni < NI; ++ni) {
      int c = wc + ni * 16 + lr;
      b[ni] = *(const bf16x8*)&BsB[c * 256 + ((ks * 64 + lk) ^ ((c & 15) << 4))];
    }
#pragma unroll
    for (int mi = 0; mi < 2; ++mi)
#pragma unroll
      for (int ni = 0; ni < NI; ++ni)
        acc[mi][ni] = __builtin_amdgcn_mfma_f32_16x16x32_bf16(a[mi], b[ni],
                                                              acc[mi][ni], 0, 0, 0);
  }

#pragma unroll
  for (int mi = 0; mi < 2; ++mi) {
#pragma unroll
    for (int reg = 0; reg < 4; ++reg) {
      int gr = row0 + wr + mi * 16 + (l >> 4) * 4 + reg;
      if (gr < n) {
#pragma unroll
        for (int ni = 0; ni < NI; ++ni) {
          int gc = wc + ni * 16 + lr;
          Y[(size_t)gr * HOUT + gc] = f2b(acc[mi][ni][reg]);
        }
      }
    }
  }
}

// ---- aggregation: wave/node, edge-phased lanes, uint2 (4 bf16) per lane ---
// BN: y = relu(acc*sc + sh); else y = acc + sh (sh = bias).
// 8 gathers in flight per phase group (two 4-batches).
template <int HOUT, bool BN, bool OUTBF>
__global__ __launch_bounds__(256) void agg_kernel(
    const unsigned short* __restrict__ h, const int* __restrict__ rowptr,
    const uint2* __restrict__ cw, const float* __restrict__ dinv,
    const float* __restrict__ sc, const float* __restrict__ sh,
    void* __restrict__ out, int n_nodes) {
  int n = (blockIdx.x * blockDim.x + threadIdx.x) >> 6;
  if (n >= n_nodes) return;
  int lane = threadIdx.x & 63;
  const uint2* hu2 = (const uint2*)h;       // 4 bf16 per uint2
  constexpr int RW2 = HOUT / 4;             // uint2 per row (32 or 16)
  constexpr int NPH = (HOUT == 128) ? 2 : 4;  // edge phases per wave
  constexpr int GL = 64 / NPH;              // lanes per phase (32 or 16)
  int phase = lane / GL;
  int sub = lane & (GL - 1);

  float dn = dinv[n];
  int beg = rowptr[n], end = rowptr[n + 1];
  float a0 = 0.f, a1 = 0.f, a2 = 0.f, a3 = 0.f;
  if (phase == 0) {
    uint2 sp = hu2[(size_t)n * RW2 + sub];
    float sw = dn * dn;
    a0 = sw * blo(sp.x); a1 = sw * bhi(sp.x);
    a2 = sw * blo(sp.y); a3 = sw * bhi(sp.y);
  }

  int j = beg + phase;
  // 8 edges per phase group in flight
  for (; j + 7 * NPH < end; j += 8 * NPH) {
    uint2 e0 = cw[j],           e1 = cw[j + NPH];
    uint2 e2 = cw[j + 2 * NPH], e3 = cw[j + 3 * NPH];
    uint2 e4 = cw[j + 4 * NPH], e5 = cw[j + 5 * NPH];
    uint2 e6 = cw[j + 6 * NPH], e7 = cw[j + 7 * NPH];
    uint2 h0 = hu2[(size_t)e0.x * RW2 + sub];
    uint2 h1 = hu2[(size_t)e1.x * RW2 + sub];
    uint2 h2 = hu2[(size_t)e2.x * RW2 + sub];
    uint2 h3 = hu2[(size_t)e3.x * RW2 + sub];
    uint2 h4 = hu2[(size_t)e4.x * RW2 + sub];
    uint2 h5 = hu2[(size_t)e5.x * RW2 + sub];
    uint2 h6 = hu2[(size_t)e6.x * RW2 + sub];
    uint2 h7 = hu2[(size_t)e7.x * RW2 + sub];
    float w0 = __uint_as_float(e0.y), w1 = __uint_as_float(e1.y);
    float w2 = __uint_as_float(e2.y), w3 = __uint_as_float(e3.y);
    float w4 = __uint_as_float(e4.y), w5 = __uint_as_float(e5.y);
    float w6 = __uint_as_float(e6.y), w7 = __uint_as_float(e7.y);
    a0 = fmaf(w0, blo(h0.x), a0); a1 = fmaf(w0, bhi(h0.x), a1);
    a2 = fmaf(w0, blo(h0.y), a2); a3 = fmaf(w0, bhi(h0.y), a3);
    a0 = fmaf(w1, blo(h1.x), a0); a1 = fmaf(w1, bhi(h1.x), a1);
    a2 = fmaf(w1, blo(h1.y), a2); a3 = fmaf(w1, bhi(h1.y), a3);
    a0 = fmaf(w2, blo(h2.x), a0); a1 = fmaf(w2, bhi(h2.x), a1);
    a2 = fmaf(w2, blo(h2.y), a2); a3 = fmaf(w2, bhi(h2.y), a3);
    a0 = fmaf(w3, blo(h3.x), a0); a1 = fmaf(w3, bhi(h3.x), a1);
    a2 = fmaf(w3, blo(h3.y), a2); a3 = fmaf(w3, bhi(h3.y), a3);
    a0 = fmaf(w4, blo(h4.x), a0); a1 = fmaf(w4, bhi(h4.x), a1);
    a2 = fmaf(w4, blo(h4.y), a2); a3 = fmaf(w4, bhi(h4.y), a3);
    a0 = fmaf(w5, blo(h5.x), a0); a1 = fmaf(w5, bhi(h5.x), a1);
    a2 = fmaf(w5, blo(h5.y), a2); a3 = fmaf(w5, bhi(h5.y), a3);
    a0 = fmaf(w6, blo(h6.x), a0); a1 = fmaf(w6, bhi(h6.x), a1);
    a2 = fmaf(w6, blo(h6.y), a2); a3 = fmaf(w6, bhi(h6.y), a3);
    a0 = fmaf(w7, blo(h7.x), a0); a1 = fmaf(w7, bhi(h7.x), a1);
    a2 = fmaf(w7, blo(h7.y), a2); a3 = fmaf(w7, bhi(h7.y), a3);
  }
  for (; j + 3 * NPH < end; j += 4 * NPH) {
    uint2 e0 = cw[j], e1 = cw[j + NPH], e2 = cw[j + 2 * NPH], e3 = cw[j + 3 * NPH];
    uint2 h0 = hu2[(size_t)e0.x * RW2 + sub];
    uint2 h1 = hu2[(size_t)e1.x * RW2 + sub];
    uint2 h2 = hu2[(size_t)e2.x * RW2 + sub];
    uint2 h3 = hu2[(size_t)e3.x * RW2 + sub];
    float w0 = __uint_as_float(e0.y), w1 = __uint_as_float(e1.y);
    float w2 = __uint_as_float(e2.y), w3 = __uint_as_float(e3.y);
    a0 = fmaf(w0, blo(h0.x), a0); a1 = fmaf(w0, bhi(h0.x), a1);
    a2 = fmaf(w0, blo(h0.y), a2); a3 = fmaf(w0, bhi(h0.y), a3);
    a0 = fmaf(w1, blo(h1.x), a0); a1 = fmaf(w1, bhi(h1.x), a1);
    a2 = fmaf(w1, blo(h1.y), a2); a3 = fmaf(w1, bhi(h1.y), a3);
    a0 = fmaf(w2, blo(h2.x), a0); a1 = fmaf(w2, bhi(h2.x), a1);
    a2 = fmaf(w2, blo(h2.y), a2); a3 = fmaf(w2, bhi(h2.y), a3);
    a0 = fmaf(w3, blo(h3.x), a0); a1 = fmaf(w3, bhi(h3.x), a1);
    a2 = fmaf(w3, blo(h3.y), a2); a3 = fmaf(w3, bhi(h3.y), a3);
  }
  for (; j < end; j += NPH) {
    uint2 e = cw[j];
    uint2 hv = hu2[(size_t)e.x * RW2 + sub];
    float w = __uint_as_float(e.y);
    a0 = fmaf(w, blo(hv.x), a0); a1 = fmaf(w, bhi(hv.x), a1);
    a2 = fmaf(w, blo(hv.y), a2); a3 = fmaf(w, bhi(hv.y), a3);
  }

  // cross-phase reduction
  a0 += __shfl_xor(a0, 32); a1 += __shfl_xor(a1, 32);
  a2 += __shfl_xor(a2, 32); a3 += __shfl_xor(a3, 32);
  if constexpr (NPH == 4) {
    a0 += __shfl_xor(a0, 16); a1 += __shfl_xor(a1, 16);
    a2 += __shfl_xor(a2, 16); a3 += __shfl_xor(a3, 16);
  }
  if (phase != 0) return;

  int c0 = sub * 4;
  float y0, y1, y2, y3;
  if constexpr (BN) {
    y0 = fmaxf(fmaf(a0, sc[c0], sh[c0]), 0.f);
    y1 = fmaxf(fmaf(a1, sc[c0 + 1], sh[c0 + 1]), 0.f);
    y2 = fmaxf(fmaf(a2, sc[c0 + 2], sh[c0 + 2]), 0.f);
    y3 = fmaxf(fmaf(a3, sc[c0 + 3], sh[c0 + 3]), 0.f);
  } else {
    y0 = a0 + sh[c0]; y1 = a1 + sh[c0 + 1];
    y2 = a2 + sh[c0 + 2]; y3 = a3 + sh[c0 + 3];
  }
  if constexpr (OUTBF) {
    unsigned p0 = (unsigned)f2b(y0) | ((unsigned)f2b(y1) << 16);
    unsigned p1 = (unsigned)f2b(y2) | ((unsigned)f2b(y3) << 16);
    ((uint2*)out)[(size_t)n * RW2 + sub] = make_uint2(p0, p1);
  } else {
    float4 o; o.x = y0; o.y = y1; o.z = y2; o.w = y3;
    *(float4*)&((float*)out)[(size_t)n * HOUT + c0] = o;
  }
}

extern "C" void kernel_launch(void* const* d_in, const int* in_sizes, int n_in,
                              void* d_out, int out_size, void* d_ws, size_t ws_size,
                              hipStream_t stream) {
  const float* x = (const float*)d_in[0];
  const int* ei32 = (const int*)d_in[1];
  const long long* ei64 = (const long long*)d_in[1];
  const float* W1 = (const float*)d_in[2];
  const float* b1 = (const float*)d_in[3];
  const float* g1 = (const float*)d_in[4];
  const float* be1 = (const float*)d_in[5];
  const float* m1 = (const float*)d_in[6];
  const float* v1 = (const float*)d_in[7];
  const float* W2 = (const float*)d_in[8];
  const float* b2 = (const float*)d_in[9];
  const float* g2 = (const float*)d_in[10];
  const float* be2 = (const float*)d_in[11];
  const float* m2 = (const float*)d_in[12];
  const float* v2 = (const float*)d_in[13];
  const float* W3 = (const float*)d_in[14];
  const float* b3 = (const float*)d_in[15];

  const int N = in_sizes[0] / 128;        // 50000
  const int E = in_sizes[1] / 2;          // 800000
  const int NBK = (N + BWID - 1) / BWID;  // 196 (<= 256)
  const int NC = NBK * NCHUNK;            // 50176

  char* ws = (char*)d_ws;
  size_t off = 0;
  auto alloc = [&](size_t bytes) -> void* {
    void* p = ws + off;
    off = (off + bytes + 255) & ~(size_t)255;
    return p;
  };
  float* dinv = (float*)alloc((size_t)N * 4);
  int* rowptr = (int*)alloc((size_t)(N + 1) * 4);
  int* degi = (int*)alloc((size_t)N * 4);
  int* counts = (int*)alloc((size_t)(NC + 1) * 4);
  int* offs = (int*)alloc((size_t)(NC + 1) * 4);
  uint2* cw = (uint2*)alloc((size_t)E * 8);
  unsigned* pairs = (unsigned*)alloc((size_t)E * 4);
  int* bsum = (int*)alloc(64 * 4);
  unsigned short* wt1 = (unsigned short*)alloc(128 * 128 * 2);
  unsigned short* wt2 = (unsigned short*)alloc(128 * 128 * 2);
  unsigned short* wt3 = (unsigned short*)alloc(128 * 64 * 2);
  float* sc1 = (float*)alloc(128 * 4);
  float* sh1 = (float*)alloc(128 * 4);
  float* sc2 = (float*)alloc(128 * 4);
  float* sh2 = (float*)alloc(128 * 4);
  unsigned short* hbuf = (unsigned short*)alloc((size_t)N * 128 * 2);  // bf16
  unsigned short* ybuf = (unsigned short*)alloc((size_t)N * 128 * 2);  // bf16
  (void)ws_size;

  wprep_kernel<<<161, 256, 0, stream>>>(W1, W2, W3, b1, g1, be1, m1, v1,
                                        b2, g2, be2, m2, v2,
                                        wt1, wt2, wt3, sc1, sh1, sc2, sh2);

  // CSR build via binning
  bin_hist_kernel<<<NCHUNK, 256, 0, stream>>>(ei32, ei64, counts, E, NBK);
  int nbC = (NC + SCAN_CHUNK - 1) / SCAN_CHUNK;  // 49
  scan_partial_kernel<<<nbC, 256, 0, stream>>>(counts, bsum, NC);
  scan_write_kernel<false><<<nbC, 256, 0, stream>>>(counts, bsum, offs, nullptr, NC, nbC);
  bin_scatter_kernel<<<NCHUNK, 256, 0, stream>>>(ei32, ei64, offs, pairs, E, NBK);
  bucket_deg_kernel<<<NBK, 256, 0, stream>>>(pairs, offs, degi, E, N, NBK);
  int nbN = (N + SCAN_CHUNK - 1) / SCAN_CHUNK;  // 49
  scan_partial_kernel<<<nbN, 256, 0, stream>>>(degi, bsum, N);
  scan_write_kernel<true><<<nbN, 256, 0, stream>>>(degi, bsum, rowptr, dinv, N, nbN);
  bucket_col_kernel<<<NBK, 256, 0, stream>>>(pairs, offs, rowptr, dinv, cw, E, N, NBK);

  int gb = (N + 63) / 64;
  int ab = (N + 3) / 4;  // one wave per node, 4 waves/block

  // layer 1
  mgemm_kernel<128, 0><<<gb, 256, 0, stream>>>(x, wt1, hbuf, N);
  agg_kernel<128, true, true><<<ab, 256, 0, stream>>>(hbuf, rowptr, cw, dinv,
                                                      sc1, sh1, ybuf, N);
  // layer 2
  mgemm_kernel<128, 1><<<gb, 256, 0, stream>>>(ybuf, wt2, hbuf, N);
  agg_kernel<128, true, true><<<ab, 256, 0, stream>>>(hbuf, rowptr, cw, dinv,
                                                      sc2, sh2, ybuf, N);
  // layer 3
  mgemm_kernel<64, 1><<<gb, 256, 0, stream>>>(ybuf, wt3, hbuf, N);
  agg_kernel<64, false, false><<<ab, 256, 0, stream>>>(hbuf, rowptr, cw, dinv,
                                                       nullptr, b3, d_out, N);
}

// Round 12
// 165.661 us; speedup vs baseline: 2.0758x; 1.1476x over previous
//
#include <hip/hip_runtime.h>

// ---------------------------------------------------------------------------
// GCN 3-layer fused pipeline for MI355X.
//   Layer l: H = bf16mfma(A_bf16 @ Wl_bf16) -> hbuf (bf16)
//   agg[n]  = dinv[n]^2*H[n] + sum_{e:dst=n} dinv[src]*dinv[n]*H[src]  (f32)
//   y = BN/bias epilogue (folded scale/shift) -> bf16 (L1,L2) / f32 (L3)
// CSR: col-only (4B/edge); weights recomputed in agg from L2-resident dinv.
// Build: histprep (hist + fused wprep) -> scan -> scatter -> bucket_merged
// (deg + scan + rowptr/dinv + col assembly in one kernel). 11 dispatches.
// ---------------------------------------------------------------------------

#define SCAN_CHUNK 1024
#define NCHUNK 256   // edge chunks (hist/scatter blocks)
#define BSHIFT 8     // dsts per bucket = 256
#define BWID 256
#define ECAP 8192    // LDS col stage capacity per bucket (mean ~4100)

typedef __attribute__((ext_vector_type(8))) short bf16x8;
typedef __attribute__((ext_vector_type(4))) float f32x4;

__device__ __forceinline__ float blo(unsigned p) { return __uint_as_float(p << 16); }
__device__ __forceinline__ float bhi(unsigned p) { return __uint_as_float(p & 0xffff0000u); }
__device__ __forceinline__ unsigned short f2b(float f) {
  unsigned u = __float_as_uint(f);
  unsigned r = (u + 0x7fffu + ((u >> 16) & 1u)) >> 16;  // RTNE
  return (unsigned short)r;
}

// ---- pass A: per-chunk bucket histogram + fused weight prep ---------------
// Blocks [0, NCHUNK): histogram. Blocks [NCHUNK, NCHUNK+161): wprep/BN fold.
__global__ __launch_bounds__(256) void histprep_kernel(
    const int* __restrict__ ei32, const long long* __restrict__ ei64,
    int* __restrict__ counts, int E, int nbk,
    const float* __restrict__ W1, const float* __restrict__ W2,
    const float* __restrict__ W3,
    const float* __restrict__ b1, const float* __restrict__ g1,
    const float* __restrict__ be1, const float* __restrict__ m1,
    const float* __restrict__ v1,
    const float* __restrict__ b2, const float* __restrict__ g2,
    const float* __restrict__ be2, const float* __restrict__ m2,
    const float* __restrict__ v2,
    unsigned short* __restrict__ Wt1, unsigned short* __restrict__ Wt2,
    unsigned short* __restrict__ Wt3,
    float* __restrict__ sc1, float* __restrict__ sh1,
    float* __restrict__ sc2, float* __restrict__ sh2) {
  __shared__ int hist[BWID];
  __shared__ int s_is32;
  int k = blockIdx.x, t = threadIdx.x;
  if (k >= NCHUNK) {  // weight-prep tail
    int i = (k - NCHUNK) * 256 + t;
    if (i < 16384) {
      int kk = i >> 7, c = i & 127;
      Wt1[c * 128 + kk] = f2b(W1[i]);
    } else if (i < 32768) {
      int j = i - 16384; int kk = j >> 7, c = j & 127;
      Wt2[c * 128 + kk] = f2b(W2[j]);
    } else if (i < 40960) {
      int j = i - 32768; int kk = j >> 6, c = j & 63;
      Wt3[c * 128 + kk] = f2b(W3[j]);
    } else if (i < 41088) {
      int c = i - 40960;
      float s = g1[c] * rsqrtf(v1[c] + 1e-5f);
      sc1[c] = s; sh1[c] = (b1[c] - m1[c]) * s + be1[c];
    } else if (i < 41216) {
      int c = i - 41088;
      float s = g2[c] * rsqrtf(v2[c] + 1e-5f);
      sc2[c] = s; sh2[c] = (b2[c] - m2[c]) * s + be2[c];
    }
    return;
  }
  hist[t] = 0;
  if (t == 0) s_is32 = 0;
  int CH = (E + NCHUNK - 1) / NCHUNK;
  int e0 = k * CH, e1 = min(e0 + CH, E);
  __syncthreads();
  // int64 data: odd words are high halves == 0; int32: random node ids.
  if (t < 64 && e0 + t < E && ei32[2 * (e0 + t) + 1] != 0) atomicOr(&s_is32, 1);
  __syncthreads();
  int is32 = s_is32;
  for (int e = e0 + t; e < e1; e += 256) {
    int d = is32 ? ei32[E + e] : (int)ei64[E + e];
    atomicAdd(&hist[d >> BSHIFT], 1);
  }
  __syncthreads();
  if (t < nbk) counts[t * NCHUNK + k] = hist[t];
}

// ---- scan: partial sums ----------------------------------------------------
__global__ __launch_bounds__(256) void scan_partial_kernel(
    const int* __restrict__ src, int* __restrict__ bsum, int n) {
  __shared__ int wsum[4];
  int b = blockIdx.x, t = threadIdx.x;
  int lane = t & 63, wv = t >> 6;
  int i0 = b * SCAN_CHUNK + t * 4;
  int4 d4 = make_int4(0, 0, 0, 0);
  if (i0 + 3 < n) d4 = *(const int4*)&src[i0];
  else {
    if (i0 < n) d4.x = src[i0];
    if (i0 + 1 < n) d4.y = src[i0 + 1];
    if (i0 + 2 < n) d4.z = src[i0 + 2];
  }
  int s = d4.x + d4.y + d4.z + d4.w;
#pragma unroll
  for (int off = 32; off; off >>= 1) s += __shfl_xor(s, off);
  if (lane == 0) wsum[wv] = s;
  __syncthreads();
  if (t == 0) bsum[b] = wsum[0] + wsum[1] + wsum[2] + wsum[3];
}

// ---- scan: write (inline bsum scan; wave 0 redundantly scans <=64 sums) ---
__global__ __launch_bounds__(256) void scan_write_kernel(
    const int* __restrict__ src, const int* __restrict__ bsum,
    int* __restrict__ outp, int n, int nb) {
  __shared__ int woff[4];
  __shared__ int s_boff;
  int b = blockIdx.x, t = threadIdx.x;
  int lane = t & 63, wv = t >> 6;
  if (t < 64) {
    int v = (t < nb) ? bsum[t] : 0;
    int ic = v;
#pragma unroll
    for (int off = 1; off < 64; off <<= 1) {
      int u = __shfl_up(ic, off);
      if (t >= off) ic += u;
    }
    if (t == b) s_boff = ic - v;
    if (b == nb - 1 && t == 63) outp[n] = ic;  // total
  }
  int i0 = b * SCAN_CHUNK + t * 4;
  int4 d4 = make_int4(0, 0, 0, 0);
  if (i0 + 3 < n) d4 = *(const int4*)&src[i0];
  else {
    if (i0 < n) d4.x = src[i0];
    if (i0 + 1 < n) d4.y = src[i0 + 1];
    if (i0 + 2 < n) d4.z = src[i0 + 2];
  }
  int tsum = d4.x + d4.y + d4.z + d4.w;
  int inc = tsum;
#pragma unroll
  for (int off = 1; off < 64; off <<= 1) {
    int u = __shfl_up(inc, off);
    if (lane >= off) inc += u;
  }
  if (lane == 63) woff[wv] = inc;
  __syncthreads();
  if (t == 0) {
    int r = 0;
#pragma unroll
    for (int w = 0; w < 4; ++w) { int sw = woff[w]; woff[w] = r; r += sw; }
  }
  __syncthreads();
  int p = inc - tsum + woff[wv] + s_boff;
  int dg[4] = {d4.x, d4.y, d4.z, d4.w};
#pragma unroll
  for (int j = 0; j < 4; ++j) {
    int i = i0 + j;
    if (i < n) outp[i] = p;
    p += dg[j];
  }
}

// ---- pass C: scatter packed (src | dst_low<<20) into bucketed runs --------
__global__ __launch_bounds__(256) void bin_scatter_kernel(
    const int* __restrict__ ei32, const long long* __restrict__ ei64,
    const int* __restrict__ offs, unsigned* __restrict__ pairs, int E, int nbk) {
  __shared__ int cur[BWID];
  __shared__ int s_is32;
  int k = blockIdx.x, t = threadIdx.x;
  if (t < nbk) cur[t] = offs[t * NCHUNK + k];
  if (t == 0) s_is32 = 0;
  int CH = (E + NCHUNK - 1) / NCHUNK;
  int e0 = k * CH, e1 = min(e0 + CH, E);
  __syncthreads();
  if (t < 64 && e0 + t < E && ei32[2 * (e0 + t) + 1] != 0) atomicOr(&s_is32, 1);
  __syncthreads();
  int is32 = s_is32;
  for (int e = e0 + t; e < e1; e += 256) {
    int s, d;
    if (is32) { s = ei32[e]; d = ei32[E + e]; }
    else      { s = (int)ei64[e]; d = (int)ei64[E + e]; }
    int pos = atomicAdd(&cur[d >> BSHIFT], 1);
    pairs[pos] = (unsigned)s | ((unsigned)(d & (BWID - 1)) << 20);
  }
}

// ---- merged bucket pass: deg -> LDS scan -> rowptr/dinv -> col assembly ---
__global__ __launch_bounds__(256) void bucket_merged_kernel(
    const unsigned* __restrict__ pairs, const int* __restrict__ offs,
    int* __restrict__ rowptr, float* __restrict__ dinv,
    int* __restrict__ col, int E, int n, int nbk) {
  __shared__ int deg[BWID];
  __shared__ int cur[BWID];
  __shared__ int woff[4];
  __shared__ int stage_s[ECAP];
  int b = blockIdx.x, t = threadIdx.x;
  int lane = t & 63, wv = t >> 6;
  deg[t] = 0;
  __syncthreads();
  int basep = offs[b * NCHUNK];
  int endp = (b + 1 < nbk) ? offs[(b + 1) * NCHUNK] : E;
  for (int i = basep + t; i < endp; i += 256)
    atomicAdd(&deg[pairs[i] >> 20], 1);
  __syncthreads();
  int dg = deg[t];
  int inc = dg;
#pragma unroll
  for (int off = 1; off < 64; off <<= 1) {
    int u = __shfl_up(inc, off);
    if (lane >= off) inc += u;
  }
  if (lane == 63) woff[wv] = inc;
  __syncthreads();
  if (t == 0) {
    int r = 0;
#pragma unroll
    for (int w = 0; w < 4; ++w) { int sw = woff[w]; woff[w] = r; r += sw; }
  }
  __syncthreads();
  int exc = inc - dg + woff[wv];
  int idx = b * BWID + t;
  if (idx < n) {
    rowptr[idx] = basep + exc;
    dinv[idx] = rsqrtf((float)(dg + 1));  // +1 self loop
  }
  cur[t] = exc;
  __syncthreads();
  for (int i = basep + t; i < endp; i += 256) {
    unsigned p = pairs[i];
    int s = (int)(p & 0xFFFFFu);
    int dl = (int)(p >> 20);
    int pos = atomicAdd(&cur[dl], 1);
    if (pos < ECAP) stage_s[pos] = s;
    else col[basep + pos] = s;
  }
  __syncthreads();
  int nE = endp - basep;
  int lim = min(nE, ECAP);
  for (int i = t; i < lim; i += 256) col[basep + i] = stage_s[i];
  if (b == 0 && t == 0) rowptr[n] = E;
}

// ---- MFMA bf16 GEMM: Y[n x HOUT](bf16) = A[n x 128] * Wt^T ----------------
template <int HOUT, int ABF16>
__global__ __launch_bounds__(256) void mgemm_kernel(
    const void* __restrict__ Ain, const unsigned short* __restrict__ Wt,
    unsigned short* __restrict__ Y, int n) {
  constexpr int NT = HOUT;
  __shared__ unsigned char AsB[64 * 256];
  __shared__ unsigned char BsB[NT * 256];
  int t = threadIdx.x;
  int row0 = blockIdx.x * 64;

  if constexpr (ABF16) {
    const unsigned short* A = (const unsigned short*)Ain;
#pragma unroll
    for (int jj = 0; jj < 4; ++jj) {
      int f = t + 256 * jj; int r = f >> 4, kq = f & 15;
      uint4 v = make_uint4(0, 0, 0, 0);
      if (row0 + r < n) v = *(const uint4*)&A[(size_t)(row0 + r) * 128 + kq * 8];
      *(uint4*)&AsB[r * 256 + ((kq * 16) ^ ((r & 15) << 4))] = v;
    }
  } else {
    const float* A = (const float*)Ain;
#pragma unroll
    for (int jj = 0; jj < 8; ++jj) {
      int f = t + 256 * jj; int r = f >> 5, kq = f & 31;
      float4 v = make_float4(0.f, 0.f, 0.f, 0.f);
      if (row0 + r < n) v = *(const float4*)&A[(size_t)(row0 + r) * 128 + kq * 4];
      unsigned two0 = (unsigned)f2b(v.x) | ((unsigned)f2b(v.y) << 16);
      unsigned two1 = (unsigned)f2b(v.z) | ((unsigned)f2b(v.w) << 16);
      uint2 o = make_uint2(two0, two1);
      *(uint2*)&AsB[r * 256 + ((kq * 8) ^ ((r & 15) << 4))] = o;
    }
  }
#pragma unroll
  for (int jj = 0; jj < NT / 16; ++jj) {
    int f = t + 256 * jj; int c = f >> 4, kq = f & 15;
    uint4 v = *(const uint4*)&Wt[(size_t)c * 128 + kq * 8];
    *(uint4*)&BsB[c * 256 + ((kq * 16) ^ ((c & 15) << 4))] = v;
  }
  __syncthreads();

  int l = t & 63, wid = t >> 6;
  constexpr int WC = NT / 2;
  constexpr int NI = WC / 16;
  int wr = (wid >> 1) * 32, wc = (wid & 1) * WC;
  int lr = l & 15, lk = (l >> 4) * 16;

  f32x4 acc[2][NI] = {};
#pragma unroll
  for (int ks = 0; ks < 4; ++ks) {
    bf16x8 a[2], b[NI];
#pragma unroll
    for (int mi = 0; mi < 2; ++mi) {
      int r = wr + mi * 16 + lr;
      a[mi] = *(const bf16x8*)&AsB[r * 256 + ((ks * 64 + lk) ^ ((r & 15) << 4))];
    }
#pragma unroll
    for (int ni = 0; ni < NI; ++ni) {
      int c = wc + ni * 16 + lr;
      b[ni] = *(const bf16x8*)&BsB[c * 256 + ((ks * 64 + lk) ^ ((c & 15) << 4))];
    }
#pragma unroll
    for (int mi = 0; mi < 2; ++mi)
#pragma unroll
      for (int ni = 0; ni < NI; ++ni)
        acc[mi][ni] = __builtin_amdgcn_mfma_f32_16x16x32_bf16(a[mi], b[ni],
                                                              acc[mi][ni], 0, 0, 0);
  }

#pragma unroll
  for (int mi = 0; mi < 2; ++mi) {
#pragma unroll
    for (int reg = 0; reg < 4; ++reg) {
      int gr = row0 + wr + mi * 16 + (l >> 4) * 4 + reg;
      if (gr < n) {
#pragma unroll
        for (int ni = 0; ni < NI; ++ni) {
          int gc = wc + ni * 16 + lr;
          Y[(size_t)gr * HOUT + gc] = f2b(acc[mi][ni][reg]);
        }
      }
    }
  }
}

// ---- aggregation: wave/node, edge-phased lanes, uint2 (4 bf16)/lane -------
// col-only CSR; w = dinv[n]*dinv[src] recomputed (dinv is L2-resident).
template <int HOUT, bool BN, bool OUTBF>
__global__ __launch_bounds__(256) void agg_kernel(
    const unsigned short* __restrict__ h, const int* __restrict__ rowptr,
    const int* __restrict__ col, const float* __restrict__ dinv,
    const float* __restrict__ sc, const float* __restrict__ sh,
    void* __restrict__ out, int n_nodes) {
  int n = (blockIdx.x * blockDim.x + threadIdx.x) >> 6;
  if (n >= n_nodes) return;
  int lane = threadIdx.x & 63;
  const uint2* hu2 = (const uint2*)h;         // 4 bf16 per uint2
  constexpr int RW2 = HOUT / 4;               // uint2 per row (32 or 16)
  constexpr int NPH = (HOUT == 128) ? 2 : 4;  // edge phases per wave
  constexpr int GL = 64 / NPH;                // lanes per phase (32 or 16)
  int phase = lane / GL;
  int sub = lane & (GL - 1);

  float dn = dinv[n];
  int beg = rowptr[n], end = rowptr[n + 1];
  float a0 = 0.f, a1 = 0.f, a2 = 0.f, a3 = 0.f;
  if (phase == 0) {
    uint2 sp = hu2[(size_t)n * RW2 + sub];
    float sw = dn * dn;
    a0 = sw * blo(sp.x); a1 = sw * bhi(sp.x);
    a2 = sw * blo(sp.y); a3 = sw * bhi(sp.y);
  }

  int j = beg + phase;
  for (; j + 3 * NPH < end; j += 4 * NPH) {
    int s0 = col[j],           s1 = col[j + NPH];
    int s2 = col[j + 2 * NPH], s3 = col[j + 3 * NPH];
    uint2 h0 = hu2[(size_t)s0 * RW2 + sub];
    uint2 h1 = hu2[(size_t)s1 * RW2 + sub];
    uint2 h2 = hu2[(size_t)s2 * RW2 + sub];
    uint2 h3 = hu2[(size_t)s3 * RW2 + sub];
    float w0 = dn * dinv[s0], w1 = dn * dinv[s1];
    float w2 = dn * dinv[s2], w3 = dn * dinv[s3];
    a0 = fmaf(w0, blo(h0.x), a0); a1 = fmaf(w0, bhi(h0.x), a1);
    a2 = fmaf(w0, blo(h0.y), a2); a3 = fmaf(w0, bhi(h0.y), a3);
    a0 = fmaf(w1, blo(h1.x), a0); a1 = fmaf(w1, bhi(h1.x), a1);
    a2 = fmaf(w1, blo(h1.y), a2); a3 = fmaf(w1, bhi(h1.y), a3);
    a0 = fmaf(w2, blo(h2.x), a0); a1 = fmaf(w2, bhi(h2.x), a1);
    a2 = fmaf(w2, blo(h2.y), a2); a3 = fmaf(w2, bhi(h2.y), a3);
    a0 = fmaf(w3, blo(h3.x), a0); a1 = fmaf(w3, bhi(h3.x), a1);
    a2 = fmaf(w3, blo(h3.y), a2); a3 = fmaf(w3, bhi(h3.y), a3);
  }
  for (; j < end; j += NPH) {
    int s = col[j];
    uint2 hv = hu2[(size_t)s * RW2 + sub];
    float w = dn * dinv[s];
    a0 = fmaf(w, blo(hv.x), a0); a1 = fmaf(w, bhi(hv.x), a1);
    a2 = fmaf(w, blo(hv.y), a2); a3 = fmaf(w, bhi(hv.y), a3);
  }

  // cross-phase reduction
  a0 += __shfl_xor(a0, 32); a1 += __shfl_xor(a1, 32);
  a2 += __shfl_xor(a2, 32); a3 += __shfl_xor(a3, 32);
  if constexpr (NPH == 4) {
    a0 += __shfl_xor(a0, 16); a1 += __shfl_xor(a1, 16);
    a2 += __shfl_xor(a2, 16); a3 += __shfl_xor(a3, 16);
  }
  if (phase != 0) return;

  int c0 = sub * 4;
  float y0, y1, y2, y3;
  if constexpr (BN) {
    y0 = fmaxf(fmaf(a0, sc[c0], sh[c0]), 0.f);
    y1 = fmaxf(fmaf(a1, sc[c0 + 1], sh[c0 + 1]), 0.f);
    y2 = fmaxf(fmaf(a2, sc[c0 + 2], sh[c0 + 2]), 0.f);
    y3 = fmaxf(fmaf(a3, sc[c0 + 3], sh[c0 + 3]), 0.f);
  } else {
    y0 = a0 + sh[c0]; y1 = a1 + sh[c0 + 1];
    y2 = a2 + sh[c0 + 2]; y3 = a3 + sh[c0 + 3];
  }
  if constexpr (OUTBF) {
    unsigned p0 = (unsigned)f2b(y0) | ((unsigned)f2b(y1) << 16);
    unsigned p1 = (unsigned)f2b(y2) | ((unsigned)f2b(y3) << 16);
    ((uint2*)out)[(size_t)n * RW2 + sub] = make_uint2(p0, p1);
  } else {
    float4 o; o.x = y0; o.y = y1; o.z = y2; o.w = y3;
    *(float4*)&((float*)out)[(size_t)n * HOUT + c0] = o;
  }
}

extern "C" void kernel_launch(void* const* d_in, const int* in_sizes, int n_in,
                              void* d_out, int out_size, void* d_ws, size_t ws_size,
                              hipStream_t stream) {
  const float* x = (const float*)d_in[0];
  const int* ei32 = (const int*)d_in[1];
  const long long* ei64 = (const long long*)d_in[1];
  const float* W1 = (const float*)d_in[2];
  const float* b1 = (const float*)d_in[3];
  const float* g1 = (const float*)d_in[4];
  const float* be1 = (const float*)d_in[5];
  const float* m1 = (const float*)d_in[6];
  const float* v1 = (const float*)d_in[7];
  const float* W2 = (const float*)d_in[8];
  const float* b2 = (const float*)d_in[9];
  const float* g2 = (const float*)d_in[10];
  const float* be2 = (const float*)d_in[11];
  const float* m2 = (const float*)d_in[12];
  const float* v2 = (const float*)d_in[13];
  const float* W3 = (const float*)d_in[14];
  const float* b3 = (const float*)d_in[15];

  const int N = in_sizes[0] / 128;        // 50000
  const int E = in_sizes[1] / 2;          // 800000
  const int NBK = (N + BWID - 1) / BWID;  // 196 (<= 256)
  const int NC = NBK * NCHUNK;            // 50176

  char* ws = (char*)d_ws;
  size_t off = 0;
  auto alloc = [&](size_t bytes) -> void* {
    void* p = ws + off;
    off = (off + bytes + 255) & ~(size_t)255;
    return p;
  };
  float* dinv = (float*)alloc((size_t)N * 4);
  int* rowptr = (int*)alloc((size_t)(N + 1) * 4);
  int* counts = (int*)alloc((size_t)(NC + 1) * 4);
  int* offs = (int*)alloc((size_t)(NC + 1) * 4);
  int* col = (int*)alloc((size_t)E * 4);
  unsigned* pairs = (unsigned*)alloc((size_t)E * 4);
  int* bsum = (int*)alloc(64 * 4);
  unsigned short* wt1 = (unsigned short*)alloc(128 * 128 * 2);
  unsigned short* wt2 = (unsigned short*)alloc(128 * 128 * 2);
  unsigned short* wt3 = (unsigned short*)alloc(128 * 64 * 2);
  float* sc1 = (float*)alloc(128 * 4);
  float* sh1 = (float*)alloc(128 * 4);
  float* sc2 = (float*)alloc(128 * 4);
  float* sh2 = (float*)alloc(128 * 4);
  unsigned short* hbuf = (unsigned short*)alloc((size_t)N * 128 * 2);  // bf16
  unsigned short* ybuf = (unsigned short*)alloc((size_t)N * 128 * 2);  // bf16
  (void)ws_size;

  // CSR build + weight prep
  histprep_kernel<<<NCHUNK + 161, 256, 0, stream>>>(
      ei32, ei64, counts, E, NBK,
      W1, W2, W3, b1, g1, be1, m1, v1, b2, g2, be2, m2, v2,
      wt1, wt2, wt3, sc1, sh1, sc2, sh2);
  int nbC = (NC + SCAN_CHUNK - 1) / SCAN_CHUNK;  // 49
  scan_partial_kernel<<<nbC, 256, 0, stream>>>(counts, bsum, NC);
  scan_write_kernel<<<nbC, 256, 0, stream>>>(counts, bsum, offs, NC, nbC);
  bin_scatter_kernel<<<NCHUNK, 256, 0, stream>>>(ei32, ei64, offs, pairs, E, NBK);
  bucket_merged_kernel<<<NBK, 256, 0, stream>>>(pairs, offs, rowptr, dinv,
                                                col, E, N, NBK);

  int gb = (N + 63) / 64;
  int ab = (N + 3) / 4;  // one wave per node, 4 waves/block

  // layer 1
  mgemm_kernel<128, 0><<<gb, 256, 0, stream>>>(x, wt1, hbuf, N);
  agg_kernel<128, true, true><<<ab, 256, 0, stream>>>(hbuf, rowptr, col, dinv,
                                                      sc1, sh1, ybuf, N);
  // layer 2
  mgemm_kernel<128, 1><<<gb, 256, 0, stream>>>(ybuf, wt2, hbuf, N);
  agg_kernel<128, true, true><<<ab, 256, 0, stream>>>(hbuf, rowptr, col, dinv,
                                                      sc2, sh2, ybuf, N);
  // layer 3
  mgemm_kernel<64, 1><<<gb, 256, 0, stream>>>(ybuf, wt3, hbuf, N);
  agg_kernel<64, false, false><<<ab, 256, 0, stream>>>(hbuf, rowptr, col, dinv,
                                                       nullptr, b3, d_out, N);
}